// Round 1
// baseline (260.816 us; speedup 1.0000x reference)
//
#include <hip/hip_runtime.h>
#include <hip/hip_bf16.h>

// RBDispatcher: fused double-gather + concat.
//   out[0 .. n_s2)        = x[ idx_s1[ idx_s2[r] ] / top_k ]
//   out[n_s2 .. n_s2+n_s1) = x[ idx_s1[r - n_s2] / top_k ]
// Pure data movement -> memory-bound. One block per output row, float4 copies.

__global__ __launch_bounds__(256) void rb_dispatch_kernel(
    const float* __restrict__ x,
    const int* __restrict__ idx_s1,
    const int* __restrict__ idx_s2,
    const int* __restrict__ top_k_ptr,
    float* __restrict__ out,
    int n_s1, int n_s2, int nvec /* d/4 */) {
  const int row = blockIdx.x;
  const int top_k = *top_k_ptr;  // device scalar, L2-cached broadcast

  int src;
  if (row < n_s2) {
    src = idx_s1[idx_s2[row]] / top_k;
  } else {
    src = idx_s1[row - n_s2] / top_k;
  }

  const int d = nvec * 4;
  const float4* __restrict__ src_ptr =
      (const float4*)(x + (size_t)src * (size_t)d);
  float4* __restrict__ dst_ptr = (float4*)(out + (size_t)row * (size_t)d);

  // d=2048 -> nvec=512 -> 2 iterations at 256 threads; fully coalesced 16B/lane.
  for (int i = threadIdx.x; i < nvec; i += blockDim.x) {
    dst_ptr[i] = src_ptr[i];
  }
}

extern "C" void kernel_launch(void* const* d_in, const int* in_sizes, int n_in,
                              void* d_out, int out_size, void* d_ws, size_t ws_size,
                              hipStream_t stream) {
  const float* x        = (const float*)d_in[0];
  const int*   idx_s1   = (const int*)d_in[1];
  const int*   idx_s2   = (const int*)d_in[2];
  // d_in[3] = n_tokens (unused), d_in[4] = top_k (device scalar)
  const int*   top_k    = (const int*)d_in[4];
  float*       out      = (float*)d_out;

  const int n_s1 = in_sizes[1];        // 16384
  const int n_s2 = in_sizes[2];        // 8192
  const int n_rows = n_s1 + n_s2;      // 24576
  const int d = out_size / n_rows;     // 2048
  const int nvec = d / 4;              // 512

  rb_dispatch_kernel<<<n_rows, 256, 0, stream>>>(
      x, idx_s1, idx_s2, top_k, out, n_s1, n_s2, nvec);
}

// Round 2
// 255.664 us; speedup vs baseline: 1.0202x; 1.0202x over previous
//
#include <hip/hip_runtime.h>
#include <hip/hip_bf16.h>

// RBDispatcher: fused double-gather + concat (pure data movement, HBM-bound).
//   out[0 .. n_s2)         = x[ idx_s1[ idx_s2[r] ] / top_k ]
//   out[n_s2 .. n_s2+n_s1) = x[ idx_s1[r - n_s2] / top_k ]
//
// R2 changes vs R1 (block-per-row, cached stores, ~115us kernel):
//  - nontemporal stores for `out` (192 MiB streaming, never re-read) so the
//    64 MiB `x` stays resident in the 256 MiB LLC for the ~137 MB of re-reads.
//  - wave-per-row, 4 rows per block: indices_s1 is sorted, so rows 2i,2i+1
//    of the s1 section read the same x row (top_k=2). Putting consecutive
//    rows in one block keeps that reuse inside one XCD's L2 (blocks
//    round-robin across the 8 non-coherent XCDs).

typedef float v4f __attribute__((ext_vector_type(4)));

__global__ __launch_bounds__(256) void rb_dispatch_kernel(
    const float* __restrict__ x,
    const int* __restrict__ idx_s1,
    const int* __restrict__ idx_s2,
    const int* __restrict__ top_k_ptr,
    float* __restrict__ out,
    int n_s2, int n_rows, int nvec /* d/4 */) {
  const int wave = threadIdx.x >> 6;
  const int lane = threadIdx.x & 63;
  const int row = blockIdx.x * 4 + wave;   // wave-uniform
  if (row >= n_rows) return;

  const int top_k = *top_k_ptr;

  int src;
  if (row < n_s2) {
    src = idx_s1[idx_s2[row]] / top_k;     // two dependent loads (s2 section)
  } else {
    src = idx_s1[row - n_s2] / top_k;      // sorted -> monotone src
  }

  const int d = nvec * 4;
  const v4f* __restrict__ sp = (const v4f*)(x + (size_t)src * (size_t)d);
  v4f* __restrict__ dp = (v4f*)(out + (size_t)row * (size_t)d);

  // nvec=512 -> 8 iterations/wave of 1 KiB coalesced each.
  #pragma unroll 4
  for (int i = lane; i < nvec; i += 64) {
    v4f v = sp[i];                          // cached read (keep x in L2/LLC)
    __builtin_nontemporal_store(v, dp + i); // streaming write, bypass caches
  }
}

extern "C" void kernel_launch(void* const* d_in, const int* in_sizes, int n_in,
                              void* d_out, int out_size, void* d_ws, size_t ws_size,
                              hipStream_t stream) {
  const float* x      = (const float*)d_in[0];
  const int*   idx_s1 = (const int*)d_in[1];
  const int*   idx_s2 = (const int*)d_in[2];
  // d_in[3] = n_tokens (unused), d_in[4] = top_k (device scalar)
  const int*   top_k  = (const int*)d_in[4];
  float*       out    = (float*)d_out;

  const int n_s1   = in_sizes[1];      // 16384
  const int n_s2   = in_sizes[2];      // 8192
  const int n_rows = n_s1 + n_s2;      // 24576
  const int d      = out_size / n_rows; // 2048
  const int nvec   = d / 4;            // 512

  const int rows_per_block = 4;        // one row per wave
  const int grid = (n_rows + rows_per_block - 1) / rows_per_block;

  rb_dispatch_kernel<<<grid, 256, 0, stream>>>(
      x, idx_s1, idx_s2, top_k, out, n_s2, n_rows, nvec);
}